// Round 1
// baseline (4090.729 us; speedup 1.0000x reference)
//
#include <hip/hip_runtime.h>
#include <hip/hip_bf16.h>

#define NN 100000
#define NE 250000
#define DD 300
#define NL 5
#define MPAD 100096   // 782*128
#define KA1 320       // padded K for GEMM1 (300->320)
#define N1 608        // padded width of m1 (600->608), also K of GEMM2
#define N1T 640       // padded rows of W1T (5 tiles * 128)
#define K2 608
#define N2T 384       // padded rows of W2T (300->384)

typedef __attribute__((ext_vector_type(8))) short short8;
typedef __attribute__((ext_vector_type(4))) float f32x4;

__device__ __forceinline__ ushort f2bf(float f){
  unsigned u = __float_as_uint(f);
  u += 0x7FFFu + ((u >> 16) & 1u);
  return (ushort)(u >> 16);
}
__device__ __forceinline__ unsigned pk2(float a, float b){
  return (unsigned)f2bf(a) | ((unsigned)f2bf(b) << 16);
}

// ---------------- weight prep: transpose + f32->bf16, zero-padded ----------
__global__ void prep_weights(const float* __restrict__ W1, const float* __restrict__ W2,
                             ushort* __restrict__ W1T, ushort* __restrict__ W2T){
  int idx = blockIdx.x * 256 + threadIdx.x;
  const int total1 = NL * N1T * KA1;
  const int total2 = NL * N2T * K2;
  if (idx < total1){
    int l = idx / (N1T * KA1);
    int rem = idx % (N1T * KA1);
    int n = rem / KA1, k = rem % KA1;
    float v = (n < 2*DD && k < DD) ? W1[(size_t)l*DD*2*DD + (size_t)k*2*DD + n] : 0.0f;
    W1T[idx] = f2bf(v);
  } else {
    int idx2 = idx - total1;
    if (idx2 < total2){
      int l = idx2 / (N2T * K2);
      int rem = idx2 % (N2T * K2);
      int n = rem / K2, k = rem % K2;
      float v = (n < DD && k < 2*DD) ? W2[(size_t)l*2*DD*DD + (size_t)k*DD + n] : 0.0f;
      W2T[idx2] = f2bf(v);
    }
  }
}

// ---------------- agg = h + self_emb (padded to [MPAD][KA1], zeros in pad) --
__global__ void init_agg(const float* __restrict__ h, const float* __restrict__ E1l,
                         const float* __restrict__ E2l, float* __restrict__ agg){
  int row = blockIdx.x;
  int d = threadIdx.x;            // 320 threads
  float v = 0.0f;
  if (row < NN && d < DD)
    v = h[(size_t)row*DD + d] + E1l[4*DD + d] + E2l[d];
  agg[(size_t)row*KA1 + d] = v;
}

// ---------------- scatter: agg[dst] += h[src] + E1[bt] + E2[bd] ------------
__global__ void scatter_add(const float* __restrict__ h, const int* __restrict__ ei,
                            const int* __restrict__ ea, const float* __restrict__ E1l,
                            const float* __restrict__ E2l, float* __restrict__ agg){
  int e = blockIdx.x;
  int d = threadIdx.x;            // 320 threads, 300 active
  if (d >= DD) return;
  int src = ei[e];
  int dst = ei[NE + e];
  int bt = ea[2*e];
  int bd = ea[2*e + 1];
  float v = h[(size_t)src*DD + d] + E1l[bt*DD + d] + E2l[bd*DD + d];
  unsafeAtomicAdd(&agg[(size_t)dst*KA1 + d], v);
}

// ---------------- bf16 MFMA GEMM, 128x128 tile, BK=32, 4 waves -------------
// A: [.. ][lda] (f32 or bf16), B: B^T bf16 [n][ldb], C: [..][ldc] (f32 or bf16)
template<int A_F32, int OUT_BF16, int RELU>
__global__ __launch_bounds__(256) void gemm_k(
    const void* __restrict__ Ap, int lda,
    const ushort* __restrict__ B, int ldb,
    void* __restrict__ Cp, int ldc,
    int kTiles, const float* __restrict__ bias, int biasN,
    int Mvalid, int Nvalid)
{
  __shared__ ushort As[128*32];
  __shared__ ushort Bs[128*32];
  int tid = threadIdx.x;
  int lane = tid & 63, w = tid >> 6;
  int wm = (w >> 1) * 64, wn = (w & 1) * 64;
  int m0 = blockIdx.x * 128, n0 = blockIdx.y * 128;

  int arow = tid >> 1;            // 0..127
  int ahalf = (tid & 1) * 16;     // 0 or 16 (elements)

  f32x4 acc[4][4] = {};

  for (int kt = 0; kt < kTiles; ++kt){
    int k0 = kt * 32;
    // stage A
    if (A_F32){
      const float* A = (const float*)Ap + (size_t)(m0 + arow)*lda + k0 + ahalf;
      float4 q0 = ((const float4*)A)[0];
      float4 q1 = ((const float4*)A)[1];
      float4 q2 = ((const float4*)A)[2];
      float4 q3 = ((const float4*)A)[3];
      uint4 p0, p1;
      p0.x = pk2(q0.x,q0.y); p0.y = pk2(q0.z,q0.w);
      p0.z = pk2(q1.x,q1.y); p0.w = pk2(q1.z,q1.w);
      p1.x = pk2(q2.x,q2.y); p1.y = pk2(q2.z,q2.w);
      p1.z = pk2(q3.x,q3.y); p1.w = pk2(q3.z,q3.w);
      *(uint4*)&As[arow*32 + ahalf]     = p0;
      *(uint4*)&As[arow*32 + ahalf + 8] = p1;
    } else {
      const ushort* A = (const ushort*)Ap + (size_t)(m0 + arow)*lda + k0 + ahalf;
      *(uint4*)&As[arow*32 + ahalf]     = ((const uint4*)A)[0];
      *(uint4*)&As[arow*32 + ahalf + 8] = ((const uint4*)A)[1];
    }
    // stage B
    {
      const ushort* Bb = B + (size_t)(n0 + arow)*ldb + k0 + ahalf;
      *(uint4*)&Bs[arow*32 + ahalf]     = ((const uint4*)Bb)[0];
      *(uint4*)&Bs[arow*32 + ahalf + 8] = ((const uint4*)Bb)[1];
    }
    __syncthreads();

    int fr = lane & 15, fk = (lane >> 4) * 8;
    short8 af[4], bfr[4];
    #pragma unroll
    for (int i = 0; i < 4; ++i)
      af[i] = *(const short8*)&As[(wm + i*16 + fr)*32 + fk];
    #pragma unroll
    for (int j = 0; j < 4; ++j)
      bfr[j] = *(const short8*)&Bs[(wn + j*16 + fr)*32 + fk];
    #pragma unroll
    for (int i = 0; i < 4; ++i)
      #pragma unroll
      for (int j = 0; j < 4; ++j)
        acc[i][j] = __builtin_amdgcn_mfma_f32_16x16x32_bf16(af[i], bfr[j], acc[i][j], 0, 0, 0);
    __syncthreads();
  }

  int cc = lane & 15, cr = (lane >> 4) * 4;
  #pragma unroll
  for (int i = 0; i < 4; ++i){
    #pragma unroll
    for (int j = 0; j < 4; ++j){
      int col = n0 + wn + j*16 + cc;
      if (col >= Nvalid) continue;
      float bv = (col < biasN) ? bias[col] : 0.0f;
      #pragma unroll
      for (int r = 0; r < 4; ++r){
        int row = m0 + wm + i*16 + cr + r;
        if (row < Mvalid){
          float v = acc[i][j][r] + bv;
          if (RELU) v = fmaxf(v, 0.0f);
          if (OUT_BF16) ((ushort*)Cp)[(size_t)row*ldc + col] = f2bf(v);
          else          ((float*) Cp)[(size_t)row*ldc + col] = v;
        }
      }
    }
  }
}

// ---------------- BN stats: per-column sum & sumsq in double ---------------
__global__ void zero_stats(double* sums){
  int i = blockIdx.x * 256 + threadIdx.x;
  if (i < 2*DD) sums[i] = 0.0;
}

__global__ void bn_stats(const float* __restrict__ m2, double* __restrict__ sums){
  int tid = threadIdx.x;          // 256
  int r0 = blockIdx.x * 128;
  double s0 = 0.0, q0 = 0.0, s1 = 0.0, q1 = 0.0;
  int c0 = tid, c1 = tid + 256;
  for (int r = 0; r < 128; ++r){
    int row = r0 + r;
    if (row >= NN) break;
    const float* mr = m2 + (size_t)row * DD;
    { float v = mr[c0]; s0 += v; q0 += (double)v * v; }
    if (c1 < DD){ float v = mr[c1]; s1 += v; q1 += (double)v * v; }
  }
  atomicAdd(&sums[c0], s0);
  atomicAdd(&sums[DD + c0], q0);
  if (c1 < DD){
    atomicAdd(&sums[c1], s1);
    atomicAdd(&sums[DD + c1], q1);
  }
}

// ---------------- BN normalize (+ optional ReLU) ---------------------------
__global__ void bn_norm(const float* __restrict__ m2, const double* __restrict__ sums,
                        const float* __restrict__ gamma, const float* __restrict__ beta,
                        float* __restrict__ out, int relu){
  int row = blockIdx.x;
  int d = threadIdx.x;            // 320 threads
  if (d >= DD) return;
  double mu_d = sums[d] / (double)NN;
  double var_d = sums[DD + d] / (double)NN - mu_d * mu_d;
  float inv = rsqrtf((float)var_d + 1e-5f);
  float mu = (float)mu_d;
  float v = (m2[(size_t)row*DD + d] - mu) * inv * gamma[d] + beta[d];
  if (relu) v = fmaxf(v, 0.0f);
  out[(size_t)row*DD + d] = v;
}

extern "C" void kernel_launch(void* const* d_in, const int* in_sizes, int n_in,
                              void* d_out, int out_size, void* d_ws, size_t ws_size,
                              hipStream_t stream) {
  const float* x     = (const float*)d_in[0];
  const int*   ei    = (const int*)  d_in[1];
  const int*   ea    = (const int*)  d_in[2];
  const float* W1    = (const float*)d_in[3];
  const float* b1    = (const float*)d_in[4];
  const float* W2    = (const float*)d_in[5];
  const float* b2    = (const float*)d_in[6];
  const float* E1    = (const float*)d_in[7];
  const float* E2    = (const float*)d_in[8];
  const float* gamma = (const float*)d_in[9];
  const float* beta  = (const float*)d_in[10];

  char* ws = (char*)d_ws;
  float* hA   = (float*)ws;  ws += (size_t)NN * DD * 4;        // 120,000,000
  float* agg  = (float*)ws;  ws += (size_t)MPAD * KA1 * 4;     // 128,122,880
  ushort* m1  = (ushort*)ws; ws += (size_t)MPAD * N1 * 2;      // 121,716,736
  ushort* W1T = (ushort*)ws; ws += (size_t)NL * N1T * KA1 * 2; //   2,048,000
  ushort* W2T = (ushort*)ws; ws += (size_t)NL * N2T * K2 * 2;  //   2,334,720
  double* sums = (double*)ws;                                  //       4,800
  float* m2 = (float*)d_out;

  // weight transpose + bf16 convert (once per launch)
  {
    int total = NL*N1T*KA1 + NL*N2T*K2;
    prep_weights<<<(total + 255)/256, 256, 0, stream>>>(W1, W2, W1T, W2T);
  }

  for (int l = 0; l < NL; ++l){
    const float* h   = (l == 0) ? x : hA;
    const float* E1l = E1 + (size_t)l * 6 * DD;
    const float* E2l = E2 + (size_t)l * 3 * DD;

    init_agg<<<MPAD, 320, 0, stream>>>(h, E1l, E2l, agg);
    scatter_add<<<NE, 320, 0, stream>>>(h, ei, ea, E1l, E2l, agg);

    // m1 = relu(agg @ W1 + b1)  -> bf16 [MPAD][608]
    gemm_k<1,1,1><<<dim3(MPAD/128, N1T/128), 256, 0, stream>>>(
        agg, KA1, W1T + (size_t)l*N1T*KA1, KA1, m1, N1, KA1/32,
        b1 + (size_t)l*2*DD, 2*DD, MPAD, N1);

    // m2 = m1 @ W2 + b2 -> f32 [NN][300] (in d_out)
    gemm_k<0,0,0><<<dim3(MPAD/128, N2T/128), 256, 0, stream>>>(
        m1, N1, W2T + (size_t)l*N2T*K2, K2, m2, DD, K2/32,
        b2 + (size_t)l*DD, DD, NN, DD);

    zero_stats<<<3, 256, 0, stream>>>(sums);
    bn_stats<<<MPAD/128, 256, 0, stream>>>(m2, sums);
    bn_norm<<<NN, 320, 0, stream>>>(m2, sums, gamma + (size_t)l*DD, beta + (size_t)l*DD,
                                    (l == NL-1) ? (float*)d_out : hA, (l < NL-1) ? 1 : 0);
  }
}

// Round 2
// 2489.272 us; speedup vs baseline: 1.6433x; 1.6433x over previous
//
#include <hip/hip_runtime.h>
#include <hip/hip_bf16.h>

#define NN 100000
#define NE 250000
#define DD 300
#define NL 5
#define MPAD 100096   // 782*128
#define KA1 320       // padded K for GEMM1 (300->320)
#define N1 608        // padded width of m1 (600->608), also K of GEMM2
#define N1T 640       // padded rows of W1T (5 tiles * 128)
#define K2 608
#define N2T 384       // padded rows of W2T (300->384)
#define NBLK 391      // ceil(NN/256); 391*256 == MPAD

typedef __attribute__((ext_vector_type(8))) short short8;
typedef __attribute__((ext_vector_type(4))) float f32x4;

#define GLBP(x) ((const __attribute__((address_space(1))) unsigned int*)(x))
#define LDSP(x) ((__attribute__((address_space(3))) unsigned int*)(x))

__device__ __forceinline__ ushort f2bf(float f){
  unsigned u = __float_as_uint(f);
  u += 0x7FFFu + ((u >> 16) & 1u);
  return (ushort)(u >> 16);
}

// ---------------- weight prep: transpose + f32->bf16, zero-padded ----------
__global__ void prep_weights(const float* __restrict__ W1, const float* __restrict__ W2,
                             ushort* __restrict__ W1T, ushort* __restrict__ W2T){
  int idx = blockIdx.x * 256 + threadIdx.x;
  const int total1 = NL * N1T * KA1;
  const int total2 = NL * N2T * K2;
  if (idx < total1){
    int l = idx / (N1T * KA1);
    int rem = idx % (N1T * KA1);
    int n = rem / KA1, k = rem % KA1;
    float v = (n < 2*DD && k < DD) ? W1[(size_t)l*DD*2*DD + (size_t)k*2*DD + n] : 0.0f;
    W1T[idx] = f2bf(v);
  } else {
    int idx2 = idx - total1;
    if (idx2 < total2){
      int l = idx2 / (N2T * K2);
      int rem = idx2 % (N2T * K2);
      int n = rem / K2, k = rem % K2;
      float v = (n < DD && k < 2*DD) ? W2[(size_t)l*2*DD*DD + (size_t)k*DD + n] : 0.0f;
      W2T[idx2] = f2bf(v);
    }
  }
}

// ---------------- CSR build ------------------------------------------------
__global__ void csr_count(const int* __restrict__ ei, int* __restrict__ deg){
  int e = blockIdx.x * 256 + threadIdx.x;
  if (e < NE) atomicAdd(&deg[ei[NE + e]], 1);
}

__global__ void scan_blk(const int* __restrict__ deg, int* __restrict__ rs, int* __restrict__ bsum){
  __shared__ int tmp[256];
  int i = blockIdx.x * 256 + threadIdx.x;
  int v = (i < NN) ? deg[i] : 0;
  tmp[threadIdx.x] = v;
  __syncthreads();
  #pragma unroll
  for (int off = 1; off < 256; off <<= 1){
    int t = (threadIdx.x >= off) ? tmp[threadIdx.x - off] : 0;
    __syncthreads();
    tmp[threadIdx.x] += t;
    __syncthreads();
  }
  if (i < NN) rs[i] = tmp[threadIdx.x] - v;   // exclusive
  if (threadIdx.x == 255) bsum[blockIdx.x] = tmp[255];
}

__global__ void scan_top(int* __restrict__ bsum){
  __shared__ int tmp[512];
  int v = (threadIdx.x < NBLK) ? bsum[threadIdx.x] : 0;
  tmp[threadIdx.x] = v;
  __syncthreads();
  #pragma unroll
  for (int off = 1; off < 512; off <<= 1){
    int t = (threadIdx.x >= off) ? tmp[threadIdx.x - off] : 0;
    __syncthreads();
    tmp[threadIdx.x] += t;
    __syncthreads();
  }
  if (threadIdx.x < NBLK) bsum[threadIdx.x] = tmp[threadIdx.x] - v; // exclusive
}

__global__ void scan_add(int* __restrict__ rs, const int* __restrict__ bsum){
  int i = blockIdx.x * 256 + threadIdx.x;
  if (i < NN) rs[i] += bsum[blockIdx.x];
  if (i == 0) rs[NN] = NE;
}

__global__ void csr_fill(const int* __restrict__ ei, const int* __restrict__ ea,
                         const int* __restrict__ rs, int* __restrict__ cursor,
                         int2* __restrict__ edges){
  int e = blockIdx.x * 256 + threadIdx.x;
  if (e < NE){
    int dst = ei[NE + e];
    int src = ei[e];
    int p = rs[dst] + atomicAdd(&cursor[dst], 1);
    edges[p] = make_int2(src, ea[2*e] | (ea[2*e+1] << 8));
  }
}

// ------- gather aggregation (+ fused norm/relu of prev layer) -> bf16 agg --
__global__ void gather_agg(const float* __restrict__ hraw, const float2* __restrict__ ss, int mode,
                           const float* __restrict__ E1l, const float* __restrict__ E2l,
                           const int* __restrict__ rs, const int2* __restrict__ edges,
                           ushort* __restrict__ agg){
  int row = blockIdx.x;
  int d = threadIdx.x;            // 320 threads
  float acc = 0.0f;
  if (row < NN && d < DD){
    float sc = 1.0f, sh = 0.0f;
    if (mode){ float2 s2 = ss[d]; sc = s2.x; sh = s2.y; }
    float hv = hraw[(size_t)row*DD + d];
    if (mode) hv = fmaxf(hv*sc + sh, 0.0f);
    acc = hv + E1l[4*DD + d] + E2l[d];       // self term
    int p = rs[row], pe = rs[row + 1];
    for (; p + 2 <= pe; p += 2){
      int2 e0 = edges[p], e1 = edges[p+1];
      float v0 = hraw[(size_t)e0.x*DD + d];
      float v1 = hraw[(size_t)e1.x*DD + d];
      if (mode){ v0 = fmaxf(v0*sc + sh, 0.0f); v1 = fmaxf(v1*sc + sh, 0.0f); }
      acc += v0 + E1l[(e0.y & 0xff)*DD + d] + E2l[(e0.y >> 8)*DD + d];
      acc += v1 + E1l[(e1.y & 0xff)*DD + d] + E2l[(e1.y >> 8)*DD + d];
    }
    if (p < pe){
      int2 e0 = edges[p];
      float v0 = hraw[(size_t)e0.x*DD + d];
      if (mode) v0 = fmaxf(v0*sc + sh, 0.0f);
      acc += v0 + E1l[(e0.y & 0xff)*DD + d] + E2l[(e0.y >> 8)*DD + d];
    }
  }
  if (d < KA1) agg[(size_t)row*KA1 + d] = f2bf(acc);
}

// ---------------- bf16 MFMA GEMM, 128x128 tile, BK=32, global_load_lds -----
template<int OUT_BF16, int RELU>
__global__ __launch_bounds__(256) void gemm_lds(
    const ushort* __restrict__ A, int lda,
    const ushort* __restrict__ B, int ldb,
    void* __restrict__ Cp, int ldc,
    int kTiles, const float* __restrict__ bias, int biasN,
    int Mvalid, int Nvalid)
{
  __shared__ ushort As[4096];
  __shared__ ushort Bs[4096];
  int tid = threadIdx.x;
  int lane = tid & 63, w = tid >> 6;
  int wm = (w >> 1) * 64, wn = (w & 1) * 64;
  int m0 = blockIdx.x * 128, n0 = blockIdx.y * 128;
  int r0 = tid >> 2;              // 0..63
  int kc = (tid & 3) * 8;         // 0,8,16,24
  const ushort* Ap = A + (size_t)(m0 + r0)*lda + kc;
  const ushort* Bp = B + (size_t)(n0 + r0)*ldb + kc;
  ushort* AsW = &As[w * 512];     // wave-uniform LDS dest (lane*16B added by HW)
  ushort* BsW = &Bs[w * 512];

  f32x4 acc[4][4] = {};

  for (int kt = 0; kt < kTiles; ++kt){
    int ko = kt * 32;
    __builtin_amdgcn_global_load_lds(GLBP(Ap + ko),                    LDSP(AsW),        16, 0, 0);
    __builtin_amdgcn_global_load_lds(GLBP(Ap + ko + (size_t)64*lda),   LDSP(AsW + 2048), 16, 0, 0);
    __builtin_amdgcn_global_load_lds(GLBP(Bp + ko),                    LDSP(BsW),        16, 0, 0);
    __builtin_amdgcn_global_load_lds(GLBP(Bp + ko + (size_t)64*ldb),   LDSP(BsW + 2048), 16, 0, 0);
    __syncthreads();

    int fr = lane & 15, fk = (lane >> 4) * 8;
    short8 af[4], bfv[4];
    #pragma unroll
    for (int i = 0; i < 4; ++i)
      af[i] = *(const short8*)&As[(wm + i*16 + fr)*32 + fk];
    #pragma unroll
    for (int j = 0; j < 4; ++j)
      bfv[j] = *(const short8*)&Bs[(wn + j*16 + fr)*32 + fk];
    #pragma unroll
    for (int i = 0; i < 4; ++i)
      #pragma unroll
      for (int j = 0; j < 4; ++j)
        acc[i][j] = __builtin_amdgcn_mfma_f32_16x16x32_bf16(af[i], bfv[j], acc[i][j], 0, 0, 0);
    __syncthreads();
  }

  int cc = lane & 15, cr = (lane >> 4) * 4;
  #pragma unroll
  for (int i = 0; i < 4; ++i){
    #pragma unroll
    for (int j = 0; j < 4; ++j){
      int col = n0 + wn + j*16 + cc;
      if (col >= Nvalid) continue;
      float bv = (col < biasN) ? bias[col] : 0.0f;
      #pragma unroll
      for (int r = 0; r < 4; ++r){
        int row = m0 + wm + i*16 + cr + r;
        if (row < Mvalid){
          float v = acc[i][j][r] + bv;
          if (RELU) v = fmaxf(v, 0.0f);
          if (OUT_BF16) ((ushort*)Cp)[(size_t)row*ldc + col] = f2bf(v);
          else          ((float*) Cp)[(size_t)row*ldc + col] = v;
        }
      }
    }
  }
}

// ---------------- BN stats: per-column sum & sumsq in double ---------------
__global__ void bn_stats(const float* __restrict__ m2, double* __restrict__ sums){
  int tid = threadIdx.x;          // 256
  int r0 = blockIdx.x * 128;
  double s0 = 0.0, q0 = 0.0, s1 = 0.0, q1 = 0.0;
  int c0 = tid, c1 = tid + 256;
  for (int r = 0; r < 128; ++r){
    int row = r0 + r;
    if (row >= NN) break;
    const float* mr = m2 + (size_t)row * DD;
    { float v = mr[c0]; s0 += v; q0 += (double)v * v; }
    if (c1 < DD){ float v = mr[c1]; s1 += v; q1 += (double)v * v; }
  }
  atomicAdd(&sums[c0], s0);
  atomicAdd(&sums[DD + c0], q0);
  if (c1 < DD){
    atomicAdd(&sums[c1], s1);
    atomicAdd(&sums[DD + c1], q1);
  }
}

// ---------------- per-column scale/shift from stats ------------------------
__global__ void make_norm(const double* __restrict__ sums, const float* __restrict__ gamma,
                          const float* __restrict__ beta, float2* __restrict__ ss){
  int d = threadIdx.x;
  if (d >= DD) return;
  double mu = sums[d] / (double)NN;
  double var = sums[DD + d] / (double)NN - mu * mu;
  float inv = rsqrtf((float)var + 1e-5f);
  float sc = inv * gamma[d];
  ss[d] = make_float2(sc, beta[d] - (float)mu * sc);
}

// ---------------- final norm (no relu) -> d_out ----------------------------
__global__ void apply_norm(const float* __restrict__ m2, const float2* __restrict__ ss,
                           float* __restrict__ out){
  int row = blockIdx.x;
  int d = threadIdx.x;
  if (d >= DD) return;
  float2 s = ss[d];
  out[(size_t)row*DD + d] = m2[(size_t)row*DD + d] * s.x + s.y;
}

extern "C" void kernel_launch(void* const* d_in, const int* in_sizes, int n_in,
                              void* d_out, int out_size, void* d_ws, size_t ws_size,
                              hipStream_t stream) {
  const float* x     = (const float*)d_in[0];
  const int*   ei    = (const int*)  d_in[1];
  const int*   ea    = (const int*)  d_in[2];
  const float* W1    = (const float*)d_in[3];
  const float* b1    = (const float*)d_in[4];
  const float* W2    = (const float*)d_in[5];
  const float* b2    = (const float*)d_in[6];
  const float* E1    = (const float*)d_in[7];
  const float* E2    = (const float*)d_in[8];
  const float* gamma = (const float*)d_in[9];
  const float* beta  = (const float*)d_in[10];

  char* p = (char*)d_ws;
  float*  m2buf = (float*) p; p += (size_t)NN * DD * 4;          // 120,000,000
  ushort* agg   = (ushort*)p; p += (size_t)MPAD * KA1 * 2;       //  64,061,440
  ushort* m1    = (ushort*)p; p += (size_t)MPAD * N1 * 2;        // 121,716,736
  ushort* W1T   = (ushort*)p; p += (size_t)NL * N1T * KA1 * 2;   //   2,048,000
  ushort* W2T   = (ushort*)p; p += (size_t)NL * N2T * K2 * 2;    //   2,334,720
  int*    deg   = (int*)   p; p += (size_t)NN * 4;               //     400,000
  int*    rs    = (int*)   p; p += (size_t)(NN + 16) * 4;        //     400,064
  int*    bsum  = (int*)   p; p += (size_t)512 * 4;              //       2,048
  int*    cursor= (int*)   p; p += (size_t)NN * 4;               //     400,000
  int2*   edges = (int2*)  p; p += (size_t)NE * 8;               //   2,000,000
  double* sums  = (double*)p; p += (size_t)2 * DD * 8;           //       4,800
  float2* ss    = (float2*)p;                                    //       2,400

  // once-per-launch prep
  {
    int total = NL*N1T*KA1 + NL*N2T*K2;
    prep_weights<<<(total + 255)/256, 256, 0, stream>>>(W1, W2, W1T, W2T);
  }
  hipMemsetAsync(deg, 0, (size_t)NN*4, stream);
  hipMemsetAsync(cursor, 0, (size_t)NN*4, stream);
  csr_count<<<(NE + 255)/256, 256, 0, stream>>>(ei, deg);
  scan_blk<<<NBLK, 256, 0, stream>>>(deg, rs, bsum);
  scan_top<<<1, 512, 0, stream>>>(bsum);
  scan_add<<<NBLK, 256, 0, stream>>>(rs, bsum);
  csr_fill<<<(NE + 255)/256, 256, 0, stream>>>(ei, ea, rs, cursor, edges);

  for (int l = 0; l < NL; ++l){
    const float* h   = (l == 0) ? x : m2buf;
    const float* E1l = E1 + (size_t)l * 6 * DD;
    const float* E2l = E2 + (size_t)l * 3 * DD;

    gather_agg<<<MPAD, 320, 0, stream>>>(h, ss, (l > 0) ? 1 : 0, E1l, E2l, rs, edges, agg);

    // m1 = relu(agg @ W1 + b1)  -> bf16 [MPAD][608]
    gemm_lds<1,1><<<dim3(MPAD/128, N1T/128), 256, 0, stream>>>(
        agg, KA1, W1T + (size_t)l*N1T*KA1, KA1, m1, N1, KA1/32,
        b1 + (size_t)l*2*DD, 2*DD, MPAD, N1);

    // m2 = m1 @ W2 + b2 -> f32 [NN][300]
    gemm_lds<0,0><<<dim3(MPAD/128, N2T/128), 256, 0, stream>>>(
        m1, N1, W2T + (size_t)l*N2T*K2, K2, m2buf, DD, K2/32,
        b2 + (size_t)l*DD, DD, NN, DD);

    hipMemsetAsync(sums, 0, (size_t)2*DD*8, stream);
    bn_stats<<<MPAD/128, 256, 0, stream>>>(m2buf, sums);
    make_norm<<<1, 320, 0, stream>>>(sums, gamma + (size_t)l*DD, beta + (size_t)l*DD, ss);
  }
  apply_norm<<<NN, 320, 0, stream>>>(m2buf, ss, (float*)d_out);
}